// Round 2
// baseline (91.880 us; speedup 1.0000x reference)
//
#include <hip/hip_runtime.h>
#include <math.h>

// Problem constants (reference: pos [64,1024,3] fp32, rad=0.15)
#define TN     64
#define NP     1024
#define RADIUS 0.15f
#define MIN_D  (2.0f * RADIUS)
#define R2     (MIN_D * MIN_D)

#define SPLIT  16      // blocks per timestep
#define GI     8       // i-rows register-tiled per j load
#define BLOCK  256

__global__ void init_ws_kernel(unsigned int* ws) {
    ws[0] = 0u;                 // count accumulator
    ((float*)ws)[1] = 0.0f;     // loss accumulator
}

__launch_bounds__(BLOCK)
__global__ void collide_kernel(const float* __restrict__ pos,
                               unsigned int* __restrict__ ws) {
    __shared__ float sh[NP * 3];                 // interleaved x,y,z (stride 3 — coprime with 32 banks)
    const int t     = blockIdx.x / SPLIT;
    const int split = blockIdx.x % SPLIT;

    // stage this timestep's 12 KB into LDS with float4 loads (3 per thread)
    const float4* p4  = (const float4*)(pos + (size_t)t * NP * 3);
    float4*       sh4 = (float4*)sh;
    #pragma unroll
    for (int k = 0; k < (NP * 3 / 4) / BLOCK; ++k)
        sh4[k * BLOCK + threadIdx.x] = p4[k * BLOCK + threadIdx.x];
    __syncthreads();

    unsigned int cnt = 0;
    float loss = 0.0f;

    // groups of GI consecutive i-rows, round-robin over the SPLIT blocks of this timestep
    for (int g = split; g < NP / GI; g += SPLIT) {
        const int b = g * GI;
        float xi[GI], yi[GI], zi[GI];
        #pragma unroll
        for (int k = 0; k < GI; ++k) {
            xi[k] = sh[3 * (b + k) + 0];
            yi[k] = sh[3 * (b + k) + 1];
            zi[k] = sh[3 * (b + k) + 2];
        }
        for (int j = b + 1 + (int)threadIdx.x; j < NP; j += BLOCK) {
            const float xj = sh[3 * j + 0];
            const float yj = sh[3 * j + 1];
            const float zj = sh[3 * j + 2];
            #pragma unroll
            for (int k = 0; k < GI; ++k) {
                const float dx = xi[k] - xj;
                const float dy = yi[k] - yj;
                const float dz = zi[k] - zj;
                const float d2 = dx * dx + dy * dy + dz * dz;
                // pair valid only if i < j (i = b+k); collisions are rare (~0.25%)
                if (d2 < R2 && j > b + k) {
                    cnt++;
                    const float pen = MIN_D - sqrtf(d2);
                    loss += pen * pen;
                }
            }
        }
    }

    // wave (64-lane) reduction
    #pragma unroll
    for (int off = 32; off > 0; off >>= 1) {
        cnt  += __shfl_down(cnt, off);
        loss += __shfl_down(loss, off);
    }
    __shared__ unsigned int cs[BLOCK / 64];
    __shared__ float        ls[BLOCK / 64];
    const int wave = threadIdx.x >> 6;
    const int lane = threadIdx.x & 63;
    if (lane == 0) { cs[wave] = cnt; ls[wave] = loss; }
    __syncthreads();
    if (threadIdx.x == 0) {
        unsigned int c = 0; float l = 0.0f;
        #pragma unroll
        for (int w = 0; w < BLOCK / 64; ++w) { c += cs[w]; l += ls[w]; }
        atomicAdd(ws, c);                       // device-scope, cross-XCD safe
        atomicAdd((float*)(ws + 1), l);
    }
}

__global__ void finalize_kernel(const unsigned int* __restrict__ ws,
                                float* __restrict__ out) {
    // Harness reads d_out as float32: write count as a float (84480 < 2^24, exact)
    out[0] = (float)ws[0];
    out[1] = ((const float*)ws)[1];
}

extern "C" void kernel_launch(void* const* d_in, const int* in_sizes, int n_in,
                              void* d_out, int out_size, void* d_ws, size_t ws_size,
                              hipStream_t stream) {
    const float*  pos = (const float*)d_in[0];
    unsigned int* ws  = (unsigned int*)d_ws;
    float*        out = (float*)d_out;

    init_ws_kernel<<<1, 1, 0, stream>>>(ws);
    collide_kernel<<<TN * SPLIT, BLOCK, 0, stream>>>(pos, ws);
    finalize_kernel<<<1, 1, 0, stream>>>(ws, out);
}

// Round 3
// 83.980 us; speedup vs baseline: 1.0941x; 1.0941x over previous
//
#include <hip/hip_runtime.h>
#include <math.h>

// Problem constants (reference: pos [64,1024,3] fp32, rad=0.15)
#define TN     64
#define NP     1024
#define RADIUS 0.15f
#define MIN_D  (2.0f * RADIUS)
#define R2     (MIN_D * MIN_D)

#define SPLIT  32                  // blocks per timestep
#define GI     16                  // i-rows register-tiled per j sweep
#define NGRP   (NP / GI)           // 64 groups per timestep
#define GPB    (NGRP / SPLIT)      // 2 groups per block
#define BLOCK  256
#define NBLK   (TN * SPLIT)        // 2048 blocks

// Each block: partial (count, loss) -> ws[2*bid], ws[2*bid+1]. No init kernel
// (plain stores, every slot written unconditionally every launch).

__launch_bounds__(BLOCK, 4)   // 4 blocks/CU -> 128 VGPR budget: i-tile stays in registers
__global__ void collide_kernel(const float* __restrict__ pos,
                               float* __restrict__ partial) {
    __shared__ float shx[NP], shy[NP], shz[NP];   // SoA: conflict-free stride-1 j reads
    const int t     = blockIdx.x / SPLIT;
    const int split = blockIdx.x % SPLIT;
    const int tid   = threadIdx.x;

    // stage this timestep's 12 KB into LDS (SoA unpack from AoS global; L2-resident)
    const float* p3 = pos + (size_t)t * NP * 3;
    #pragma unroll
    for (int i = 0; i < NP / BLOCK; ++i) {
        const int p = tid + i * BLOCK;
        shx[p] = p3[3 * p + 0];
        shy[p] = p3[3 * p + 1];
        shz[p] = p3[3 * p + 2];
    }
    __syncthreads();

    float cnt = 0.0f;   // block-partial count (exact in fp32, < 2^24)
    float loss = 0.0f;

    #pragma unroll
    for (int m = 0; m < GPB; ++m) {
        // snake assignment: block handles groups g = split and (NGRP-1-split),
        // so per-block total j-length is constant -> perfect load balance
        const int g = (m & 1) ? (m * SPLIT + (SPLIT - 1 - split))
                              : (m * SPLIT + split);
        const int b = g * GI;

        float xi[GI], yi[GI], zi[GI];
        #pragma unroll
        for (int k = 0; k < GI; ++k) {
            xi[k] = shx[b + k];
            yi[k] = shy[b + k];
            zi[k] = shz[b + k];
        }

        // head: j in [b+1, b+GI) needs the i<j mask; one lane per j
        if (tid < GI - 1) {
            const int j = b + 1 + tid;
            const float xj = shx[j], yj = shy[j], zj = shz[j];
            #pragma unroll
            for (int k = 0; k < GI; ++k) {
                if (k <= tid) {   // i = b+k < j
                    const float dx = xi[k] - xj;
                    const float dy = yi[k] - yj;
                    const float dz = zi[k] - zj;
                    const float d2 = dx * dx + dy * dy + dz * dz;
                    if (d2 < R2) {
                        cnt += 1.0f;
                        const float pen = MIN_D - sqrtf(d2);
                        loss += pen * pen;
                    }
                }
            }
        }

        // tail: j >= b+GI -> all GI i-rows valid, no mask (7 VALU/pair)
        for (int j = b + GI + tid; j < NP; j += BLOCK) {
            const float xj = shx[j], yj = shy[j], zj = shz[j];
            #pragma unroll
            for (int k = 0; k < GI; ++k) {
                const float dx = xi[k] - xj;
                const float dy = yi[k] - yj;
                const float dz = zi[k] - zj;
                const float d2 = dx * dx + dy * dy + dz * dz;
                if (d2 < R2) {
                    cnt += 1.0f;
                    const float pen = MIN_D - sqrtf(d2);
                    loss += pen * pen;
                }
            }
        }
    }

    // wave (64-lane) reduction, then cross-wave via LDS
    #pragma unroll
    for (int off = 32; off > 0; off >>= 1) {
        cnt  += __shfl_down(cnt, off);
        loss += __shfl_down(loss, off);
    }
    __shared__ float cs[BLOCK / 64], ls[BLOCK / 64];
    const int wave = tid >> 6;
    if ((tid & 63) == 0) { cs[wave] = cnt; ls[wave] = loss; }
    __syncthreads();
    if (tid == 0) {
        float c = 0.0f, l = 0.0f;
        #pragma unroll
        for (int w = 0; w < BLOCK / 64; ++w) { c += cs[w]; l += ls[w]; }
        partial[2 * blockIdx.x + 0] = c;
        partial[2 * blockIdx.x + 1] = l;
    }
}

__global__ void finalize_kernel(const float* __restrict__ partial,
                                float* __restrict__ out) {
    const int tid = threadIdx.x;
    float c = 0.0f, l = 0.0f;
    #pragma unroll
    for (int i = 0; i < NBLK / BLOCK; ++i) {
        const float2 p = ((const float2*)partial)[tid + i * BLOCK];
        c += p.x;
        l += p.y;
    }
    #pragma unroll
    for (int off = 32; off > 0; off >>= 1) {
        c += __shfl_down(c, off);
        l += __shfl_down(l, off);
    }
    __shared__ float cs[BLOCK / 64], ls[BLOCK / 64];
    const int wave = tid >> 6;
    if ((tid & 63) == 0) { cs[wave] = c; ls[wave] = l; }
    __syncthreads();
    if (tid == 0) {
        float ct = 0.0f, lt = 0.0f;
        #pragma unroll
        for (int w = 0; w < BLOCK / 64; ++w) { ct += cs[w]; lt += ls[w]; }
        out[0] = ct;   // harness reads d_out as float32; count exact (< 2^24)
        out[1] = lt;
    }
}

extern "C" void kernel_launch(void* const* d_in, const int* in_sizes, int n_in,
                              void* d_out, int out_size, void* d_ws, size_t ws_size,
                              hipStream_t stream) {
    const float* pos     = (const float*)d_in[0];
    float*       partial = (float*)d_ws;
    float*       out     = (float*)d_out;

    collide_kernel<<<NBLK, BLOCK, 0, stream>>>(pos, partial);
    finalize_kernel<<<1, BLOCK, 0, stream>>>(partial, out);
}